// Round 16
// baseline (1311.864 us; speedup 1.0000x reference)
//
#include <hip/hip_runtime.h>

#define N_NODES 50000
#define N_EDGES 800000
#define IN_DIM  512
#define HID     256
#define LAT     128
#define K_ITERS 10
#define BN_EPS  1e-5f

typedef __attribute__((ext_vector_type(8))) short bf16x8;
typedef __attribute__((ext_vector_type(4))) float f32x4;
typedef __attribute__((ext_vector_type(4))) unsigned u32x4;

// ---------------- bf16 helpers ----------------
__device__ inline float bflo(unsigned v) { return __builtin_bit_cast(float, v << 16); }
__device__ inline float bfhi(unsigned v) { return __builtin_bit_cast(float, v & 0xffff0000u); }
__device__ inline unsigned f2bf_bits(float f)
{
    unsigned u = __builtin_bit_cast(unsigned, f);
    return (u + 0x7fffu + ((u >> 16) & 1u)) >> 16;   // RTNE
}
__device__ inline unsigned packbf(float x, float y)
{
    return f2bf_bits(x) | (f2bf_bits(y) << 16);
}

// async global->LDS, 16B per lane; LDS dest = uniform base + lane*16
__device__ inline void gload_lds16(const unsigned short* g, unsigned short* l)
{
    __builtin_amdgcn_global_load_lds(
        (const __attribute__((address_space(1))) unsigned int*)g,
        (__attribute__((address_space(3))) unsigned int*)l, 16, 0, 0);
}

// ---------------- edge dtype detect / normalize ----------------
__global__ void detect_dtype_kernel(const int* __restrict__ ei32, int* __restrict__ flag)
{
    __shared__ int any;
    if (threadIdx.x == 0) any = 0;
    __syncthreads();
    int local = 0;
    for (int i = threadIdx.x; i < 4096; i += blockDim.x)
        local |= ei32[2 * i + 1];
    if (local) atomicOr(&any, 1);
    __syncthreads();
    if (threadIdx.x == 0) flag[0] = (any != 0) ? 1 : 0;   // 1 => data is int32
}

__global__ void init_cnt_kernel(int* __restrict__ cnt, int n)
{
    int i = blockIdx.x * blockDim.x + threadIdx.x;
    if (i < n) cnt[i] = 1;   // self-loop
}

// fused convert + degree count
__global__ void convert_count_kernel(const void* __restrict__ ei, const int* __restrict__ flag,
                                     int* __restrict__ srcE, int* __restrict__ dstE,
                                     int* __restrict__ cnt, int E)
{
    int e = blockIdx.x * blockDim.x + threadIdx.x;
    if (e >= E) return;
    int s, d;
    if (*flag) {
        const int* p = (const int*)ei;
        s = p[e]; d = p[E + e];
    } else {
        const long long* p = (const long long*)ei;
        s = (int)p[e]; d = (int)p[E + e];
    }
    srcE[e] = s;
    dstE[e] = d;
    atomicAdd(&cnt[d], 1);
}

// ---------------- parallel scan (3 small kernels) ----------------
__global__ __launch_bounds__(256) void block_sum_kernel(const int* __restrict__ cnt,
                                                        int* __restrict__ bsum, int n)
{
    __shared__ int s[256];
    int i = blockIdx.x * 256 + threadIdx.x;
    s[threadIdx.x] = (i < n) ? cnt[i] : 0;
    __syncthreads();
    for (int off = 128; off > 0; off >>= 1) {
        if (threadIdx.x < off) s[threadIdx.x] += s[threadIdx.x + off];
        __syncthreads();
    }
    if (threadIdx.x == 0) bsum[blockIdx.x] = s[0];
}

__global__ __launch_bounds__(256) void block_scan_kernel(int* __restrict__ bsum, int nb)
{
    __shared__ int s[256];
    int t = threadIdx.x;
    int v = (t < nb) ? bsum[t] : 0;
    s[t] = v;
    __syncthreads();
    for (int off = 1; off < 256; off <<= 1) {
        int u = (t >= off) ? s[t - off] : 0;
        __syncthreads();
        s[t] += u;
        __syncthreads();
    }
    if (t < nb) bsum[t] = s[t] - v;   // exclusive block offsets
}

__global__ __launch_bounds__(256) void final_scan_kernel(const int* __restrict__ cnt,
                                                         const int* __restrict__ bsum,
                                                         int* __restrict__ rowoff,
                                                         int* __restrict__ cursor,
                                                         float* __restrict__ dinv, int n)
{
    __shared__ int s[256];
    int t = threadIdx.x;
    int i = blockIdx.x * 256 + t;
    int c = (i < n) ? cnt[i] : 0;
    s[t] = c;
    __syncthreads();
    for (int off = 1; off < 256; off <<= 1) {
        int u = (t >= off) ? s[t - off] : 0;
        __syncthreads();
        s[t] += u;
        __syncthreads();
    }
    if (i < n) {
        int excl = bsum[blockIdx.x] + s[t] - c;
        rowoff[i] = excl;
        cursor[i] = excl;
        dinv[i] = rsqrtf((float)c);
    }
    if (i == 0) rowoff[n] = N_EDGES + N_NODES;   // total is a constant
}

// csr entry packed: src (16 bits, N<65536) | bf16(w) << 16
__global__ void scatter_kernel(const int* __restrict__ srcE, const int* __restrict__ dstE,
                               const float* __restrict__ dinv, int* __restrict__ cursor,
                               unsigned* __restrict__ csr, int E, int n)
{
    int e = blockIdx.x * blockDim.x + threadIdx.x;
    if (e >= E + n) return;
    int s, d;
    if (e < E) { s = srcE[e]; d = dstE[e]; }
    else       { s = e - E;   d = s; }
    int pos = atomicAdd(&cursor[d], 1);
    float w = dinv[s] * dinv[d];
    csr[pos] = (unsigned)s | (f2bf_bits(w) << 16);
}

// ---- transpose-convert to tile-major bf16: W[K][C] -> [colblk][k/8][128][8] --
__global__ void transpose_cvt_tile(const float* __restrict__ in, unsigned short* __restrict__ out,
                                   int K, int C)
{
    int idx = blockIdx.x * 256 + threadIdx.x;
    if (idx >= K * C) return;
    int k = idx / C, col = idx - k * C;
    int dst = (col >> 7) * (K * 128) + (k >> 3) * 1024 + ((col & 127) << 3) + (k & 7);
    out[dst] = (unsigned short)f2bf_bits(in[idx]);
}

// ---------------- MFMA bf16 GEMM, global_load_lds B-staging ------------------
// 16 rows/wave x 128 cols, 4 waves/block (64-row tile). Grid (Nc/128, ceil(M/64)).
// B pre-laid tile-major so each 64-k chunk (16 KB) is a LINEAR lane-order copy
// -> global_load_lds (no staging registers: nothing to spill or sink).
// Double-buffered LDS, one barrier per chunk. A: 2-deep register prefetch.
template<int KDIM, int EPI, bool AF32>
__global__ __launch_bounds__(256) void gemm_lds(const void* __restrict__ Ain,
                                                const unsigned short* __restrict__ Bt,
                                                unsigned short* __restrict__ Cout,
                                                int M, int Nc,
                                                const float* __restrict__ cb,
                                                const float* __restrict__ cg,
                                                const float* __restrict__ cbe,
                                                const float* __restrict__ cm,
                                                const float* __restrict__ cv)
{
    constexpr int BK = 64;
    constexpr int NC = KDIM / BK;
    __shared__ unsigned short Bl[2][BK * 128];   // 2 x 16 KB
    const int tid  = threadIdx.x;
    const int wave = tid >> 6;
    const int lane = tid & 63;
    const int s  = lane & 15;
    const int kc = lane >> 4;
    const int wrow0   = blockIdx.y * 64 + wave * 16;
    const int colbase = blockIdx.x * 128;
    int arow = wrow0 + s; if (arow > M - 1) arow = M - 1;   // clamp

    const float*          Af   = (const float*)Ain + (size_t)arow * KDIM + 8 * kc;
    const unsigned short* Ahp  = (const unsigned short*)Ain + (size_t)arow * KDIM + 8 * kc;
    const unsigned short* Bblk = Bt + (size_t)blockIdx.x * KDIM * 128;

    float4 Arf[2][2][2];
    bf16x8 Arh[2][2];
    f32x4  acc[8] = {};

    auto stage = [&](int c, int buf) {
#pragma unroll
        for (int i = 0; i < 4; ++i) {
            const int j = wave * 4 + i;
            gload_lds16(Bblk + (size_t)c * 8192 + j * 512 + lane * 8, &Bl[buf][j * 512]);
        }
    };

    stage(0, 0);
#pragma unroll
    for (int kk = 0; kk < 2; ++kk) {
        if constexpr (AF32) {
            Arf[0][kk][0] = *(const float4*)(Af + 32 * kk);
            Arf[0][kk][1] = *(const float4*)(Af + 32 * kk + 4);
        } else {
            Arh[0][kk] = *(const bf16x8*)(Ahp + 32 * kk);
        }
    }
    __syncthreads();   // drains chunk-0 DMA

#pragma unroll
    for (int c = 0; c < NC; ++c) {
        if (c + 1 < NC) {
            stage(c + 1, (c + 1) & 1);
#pragma unroll
            for (int kk = 0; kk < 2; ++kk) {
                if constexpr (AF32) {
                    Arf[(c + 1) & 1][kk][0] = *(const float4*)(Af + (c + 1) * 64 + 32 * kk);
                    Arf[(c + 1) & 1][kk][1] = *(const float4*)(Af + (c + 1) * 64 + 32 * kk + 4);
                } else {
                    Arh[(c + 1) & 1][kk] = *(const bf16x8*)(Ahp + (c + 1) * 64 + 32 * kk);
                }
            }
        }
#pragma unroll
        for (int kk = 0; kk < 2; ++kk) {
            bf16x8 af;
            if constexpr (AF32) {
                float4 u0 = Arf[c & 1][kk][0];
                float4 u1 = Arf[c & 1][kk][1];
                af[0] = (short)f2bf_bits(u0.x); af[1] = (short)f2bf_bits(u0.y);
                af[2] = (short)f2bf_bits(u0.z); af[3] = (short)f2bf_bits(u0.w);
                af[4] = (short)f2bf_bits(u1.x); af[5] = (short)f2bf_bits(u1.y);
                af[6] = (short)f2bf_bits(u1.z); af[7] = (short)f2bf_bits(u1.w);
            } else {
                af = Arh[c & 1][kk];
            }
#pragma unroll
            for (int t = 0; t < 8; ++t) {
                bf16x8 bf = *(const bf16x8*)&Bl[c & 1][((kk * 4 + kc) * 128 + t * 16 + s) * 8];
                acc[t] = __builtin_amdgcn_mfma_f32_16x16x32_bf16(af, bf, acc[t], 0, 0, 0);
            }
        }
        __syncthreads();
    }

#pragma unroll
    for (int t = 0; t < 8; ++t) {
        const int col = colbase + t * 16 + s;
        float sc = 1.f, sh = 0.f;
        if (EPI == 1) {
            sc = cg[col] * rsqrtf(cv[col] + BN_EPS);
            sh = (cb[col] - cm[col]) * sc + cbe[col];
        }
#pragma unroll
        for (int j = 0; j < 4; ++j) {
            const int crow = wrow0 + kc * 4 + j;
            if (crow < M) {
                float xv = acc[t][j];
                if (EPI == 1) xv = fmaxf(fmaf(xv, sc, sh), 0.f);
                Cout[(size_t)crow * Nc + col] = (unsigned short)f2bf_bits(xv);
            }
        }
    }
}

// ---------------- full-row propagate, 2 nodes/wave (R12 best config) ---------
// Half-wave (32 lanes) per node: 2 edge-groups x 16 lanes; lane covers dims
// 8s..8s+7 (uint4). Predicated 8-deep gather batch (compiler serializes to a
// low-VGPR schedule -> high occupancy; props are BW-bound at this point).
// csr 4B packed (src:16 | bf16(w):16).
// MODE 0: out bf16. MODE 1: bn+relu -> bf16. MODE 2: 0.9a+0.1h2 -> bf16.
// MODE 3: final: f32 z to outf, bf16 mirror to outh (aliases z0h).
template<int MODE>
__global__ __launch_bounds__(256) void prop_row(const unsigned* __restrict__ in,
                                                const int* __restrict__ rowoff,
                                                const unsigned* __restrict__ csr,
                                                const unsigned* __restrict__ h2h,
                                                const unsigned* __restrict__ z0h,
                                                float* __restrict__ outf,
                                                unsigned* __restrict__ outh,
                                                const float* __restrict__ bb,
                                                const float* __restrict__ bg,
                                                const float* __restrict__ bbe,
                                                const float* __restrict__ bm,
                                                const float* __restrict__ bv)
{
    const int node = blockIdx.x * 8 + (threadIdx.x >> 5);   // half-wave -> node
    const int lane = threadIdx.x & 31;
    const int g = lane >> 4, s = lane & 15;
    const int e0 = rowoff[node], e1 = rowoff[node + 1];

    float f[8] = {};
    int e = e0 + g;
    while (e < e1) {
        unsigned P[8];
        u32x4 V[8];
#pragma unroll
        for (int i = 0; i < 8; ++i) { P[i] = 0; V[i] = (u32x4){0u, 0u, 0u, 0u}; }
#pragma unroll
        for (int i = 0; i < 8; ++i)
            if (e + 2 * i < e1) P[i] = csr[e + 2 * i];
#pragma unroll
        for (int i = 0; i < 8; ++i)
            if (e + 2 * i < e1) V[i] = *(const u32x4*)&in[(size_t)(P[i] & 0xFFFFu) * 64 + 4 * s];
#pragma unroll
        for (int i = 0; i < 8; ++i) {
            const float w = __builtin_bit_cast(float, P[i] & 0xffff0000u);
            f[0] = fmaf(w, bflo(V[i].x), f[0]); f[1] = fmaf(w, bfhi(V[i].x), f[1]);
            f[2] = fmaf(w, bflo(V[i].y), f[2]); f[3] = fmaf(w, bfhi(V[i].y), f[3]);
            f[4] = fmaf(w, bflo(V[i].z), f[4]); f[5] = fmaf(w, bfhi(V[i].z), f[5]);
            f[6] = fmaf(w, bflo(V[i].w), f[6]); f[7] = fmaf(w, bfhi(V[i].w), f[7]);
        }
        e += 16;
    }
#pragma unroll
    for (int i = 0; i < 8; ++i)
        f[i] += __shfl_xor(f[i], 16, 64);   // combine the node's 2 groups

    if (g == 0) {
        const size_t o = (size_t)node * 64 + 4 * s;
        u32x4 ov;
        if (MODE == 0) {
            ov.x = packbf(f[0], f[1]); ov.y = packbf(f[2], f[3]);
            ov.z = packbf(f[4], f[5]); ov.w = packbf(f[6], f[7]);
            *(u32x4*)&outh[o] = ov;
        } else if (MODE == 1) {
            float4 G0 = *(const float4*)&bg[8 * s],  G1 = *(const float4*)&bg[8 * s + 4];
            float4 V0 = *(const float4*)&bv[8 * s],  V1 = *(const float4*)&bv[8 * s + 4];
            float4 B0 = *(const float4*)&bb[8 * s],  B1 = *(const float4*)&bb[8 * s + 4];
            float4 M0 = *(const float4*)&bm[8 * s],  M1 = *(const float4*)&bm[8 * s + 4];
            float4 E0 = *(const float4*)&bbe[8 * s], E1 = *(const float4*)&bbe[8 * s + 4];
            float gg[8] = {G0.x, G0.y, G0.z, G0.w, G1.x, G1.y, G1.z, G1.w};
            float vv[8] = {V0.x, V0.y, V0.z, V0.w, V1.x, V1.y, V1.z, V1.w};
            float bbv[8] = {B0.x, B0.y, B0.z, B0.w, B1.x, B1.y, B1.z, B1.w};
            float mm[8] = {M0.x, M0.y, M0.z, M0.w, M1.x, M1.y, M1.z, M1.w};
            float ee[8] = {E0.x, E0.y, E0.z, E0.w, E1.x, E1.y, E1.z, E1.w};
            float r[8];
#pragma unroll
            for (int i = 0; i < 8; ++i) {
                float sc = gg[i] * rsqrtf(vv[i] + BN_EPS);
                float sh = (bbv[i] - mm[i]) * sc + ee[i];
                r[i] = fmaxf(fmaf(f[i], sc, sh), 0.f);
            }
            ov.x = packbf(r[0], r[1]); ov.y = packbf(r[2], r[3]);
            ov.z = packbf(r[4], r[5]); ov.w = packbf(r[6], r[7]);
            *(u32x4*)&outh[o] = ov;
        } else if (MODE == 2) {
            u32x4 hv = *(const u32x4*)&h2h[o];
            ov.x = packbf(fmaf(0.9f, f[0], 0.1f * bflo(hv.x)), fmaf(0.9f, f[1], 0.1f * bfhi(hv.x)));
            ov.y = packbf(fmaf(0.9f, f[2], 0.1f * bflo(hv.y)), fmaf(0.9f, f[3], 0.1f * bfhi(hv.y)));
            ov.z = packbf(fmaf(0.9f, f[4], 0.1f * bflo(hv.z)), fmaf(0.9f, f[5], 0.1f * bfhi(hv.z)));
            ov.w = packbf(fmaf(0.9f, f[6], 0.1f * bflo(hv.w)), fmaf(0.9f, f[7], 0.1f * bfhi(hv.w)));
            *(u32x4*)&outh[o] = ov;
        } else {
            u32x4 hv = *(const u32x4*)&h2h[o];
            u32x4 zv = *(const u32x4*)&z0h[o];
            float r[8];
            r[0] = fmaf(0.9f, f[0], 0.1f * bflo(hv.x)) + bflo(zv.x);
            r[1] = fmaf(0.9f, f[1], 0.1f * bfhi(hv.x)) + bfhi(zv.x);
            r[2] = fmaf(0.9f, f[2], 0.1f * bflo(hv.y)) + bflo(zv.y);
            r[3] = fmaf(0.9f, f[3], 0.1f * bfhi(hv.y)) + bfhi(zv.y);
            r[4] = fmaf(0.9f, f[4], 0.1f * bflo(hv.z)) + bflo(zv.z);
            r[5] = fmaf(0.9f, f[5], 0.1f * bfhi(hv.z)) + bfhi(zv.z);
            r[6] = fmaf(0.9f, f[6], 0.1f * bflo(hv.w)) + bflo(zv.w);
            r[7] = fmaf(0.9f, f[7], 0.1f * bfhi(hv.w)) + bfhi(zv.w);
            *(float4*)&outf[(size_t)node * LAT + 8 * s]     = make_float4(r[0], r[1], r[2], r[3]);
            *(float4*)&outf[(size_t)node * LAT + 8 * s + 4] = make_float4(r[4], r[5], r[6], r[7]);
            ov.x = packbf(r[0], r[1]); ov.y = packbf(r[2], r[3]);
            ov.z = packbf(r[4], r[5]); ov.w = packbf(r[6], r[7]);
            *(u32x4*)&outh[o] = ov;
        }
    }
}

// ---------------- MFMA edge dot: 16 edges per wave, row-major z --------------
__global__ __launch_bounds__(256) void edge_dot_mfma(const unsigned* __restrict__ zh,
                                                     const int* __restrict__ srcE,
                                                     const int* __restrict__ dstE,
                                                     float* __restrict__ adj)
{
    const int gw = blockIdx.x * 4 + (threadIdx.x >> 6);
    const int base = gw * 16;
    const int lane = threadIdx.x & 63;
    const int s = lane & 15, kc = lane >> 4;
    const int r = srcE[base + s];
    const int c = dstE[base + s];
    const unsigned* zr = &zh[(size_t)r * 64 + 4 * kc];
    const unsigned* zc = &zh[(size_t)c * 64 + 4 * kc];
    f32x4 acc = {};
#pragma unroll
    for (int k0 = 0; k0 < 4; ++k0) {
        bf16x8 af = *(const bf16x8*)(zr + 16 * k0);
        bf16x8 bf = *(const bf16x8*)(zc + 16 * k0);
        acc = __builtin_amdgcn_mfma_f32_16x16x32_bf16(af, bf, acc, 0, 0, 0);
    }
    if ((s >> 2) == kc) {
        const int j = s & 3;
        float v = (j == 0) ? acc[0] : (j == 1) ? acc[1] : (j == 2) ? acc[2] : acc[3];
        adj[base + s] = 1.f / (1.f + expf(-v));
    }
}

// ---------------- launcher ----------------
extern "C" void kernel_launch(void* const* d_in, const int* in_sizes, int n_in,
                              void* d_out, int out_size, void* d_ws, size_t ws_size,
                              hipStream_t stream)
{
    const float* x     = (const float*)d_in[0];
    const void*  ei    = d_in[1];
    const float* Wproj = (const float*)d_in[2];
    const float* W1    = (const float*)d_in[3];
    const float* b1    = (const float*)d_in[4];
    const float* g1    = (const float*)d_in[5];
    const float* be1   = (const float*)d_in[6];
    const float* m1    = (const float*)d_in[7];
    const float* v1    = (const float*)d_in[8];
    const float* W2    = (const float*)d_in[9];
    const float* b2    = (const float*)d_in[10];
    const float* g2    = (const float*)d_in[11];
    const float* be2   = (const float*)d_in[12];
    const float* m2    = (const float*)d_in[13];
    const float* v2    = (const float*)d_in[14];

    float* out_adj = (float*)d_out;
    float* out_z   = (float*)d_out + N_EDGES;

    char* w = (char*)d_ws;
    size_t off = 0;
    auto alloc = [&](size_t bytes) {
        void* p = w + off;
        off += (bytes + 255) & ~(size_t)255;
        return p;
    };
    const size_t NB = (size_t)N_NODES * 64 * 4;   // one bf16 [N,128] plane = 12.8 MB
    const int NBLK = (N_NODES + 255) / 256;       // 196

    int*            flag   = (int*)           alloc(4);
    int*            cnt    = (int*)           alloc((size_t)N_NODES * 4);
    int*            cursor = (int*)           alloc((size_t)N_NODES * 4);
    int*            rowoff = (int*)           alloc((size_t)(N_NODES + 1) * 4);
    float*          dinv   = (float*)         alloc((size_t)N_NODES * 4);
    int*            bsum   = (int*)           alloc(256 * 4);
    int*            srcE   = (int*)           alloc((size_t)N_EDGES * 4);
    int*            dstE   = (int*)           alloc((size_t)N_EDGES * 4);
    unsigned*       csr    = (unsigned*)      alloc((size_t)(N_EDGES + N_NODES) * 4);
    unsigned short* Wpt    = (unsigned short*)alloc((size_t)LAT * IN_DIM * 2);
    unsigned short* W1t    = (unsigned short*)alloc((size_t)HID * LAT * 2);
    unsigned short* W2t    = (unsigned short*)alloc((size_t)LAT * HID * 2);
    unsigned*       z0h    = (unsigned*)      alloc(NB);       // z0 bf16; final z mirror
    unsigned*       p0h    = (unsigned*)      alloc(NB);
    unsigned short* h1h    = (unsigned short*)alloc(2 * NB);   // [N,256]; later pingA/pingB
    unsigned*       t2h    = (unsigned*)      alloc(NB);
    unsigned*       h2h    = (unsigned*)      alloc(NB);

    unsigned* pingA = (unsigned*)h1h;
    unsigned* pingB = (unsigned*)h1h + N_NODES * 64;

    // graph preprocessing
    detect_dtype_kernel<<<1, 256, 0, stream>>>((const int*)ei, flag);
    init_cnt_kernel<<<(N_NODES + 255) / 256, 256, 0, stream>>>(cnt, N_NODES);
    convert_count_kernel<<<(N_EDGES + 255) / 256, 256, 0, stream>>>(ei, flag, srcE, dstE, cnt, N_EDGES);
    block_sum_kernel<<<NBLK, 256, 0, stream>>>(cnt, bsum, N_NODES);
    block_scan_kernel<<<1, 256, 0, stream>>>(bsum, NBLK);
    final_scan_kernel<<<NBLK, 256, 0, stream>>>(cnt, bsum, rowoff, cursor, dinv, N_NODES);
    scatter_kernel<<<(N_EDGES + N_NODES + 255) / 256, 256, 0, stream>>>(srcE, dstE, dinv, cursor,
                                                                        csr, N_EDGES, N_NODES);

    // weight transposes (f32 -> bf16, tile-major [colblk][k/8][128][8])
    transpose_cvt_tile<<<(IN_DIM * LAT + 255) / 256, 256, 0, stream>>>(Wproj, Wpt, IN_DIM, LAT);
    transpose_cvt_tile<<<(LAT * HID + 255) / 256, 256, 0, stream>>>(W1, W1t, LAT, HID);
    transpose_cvt_tile<<<(HID * LAT + 255) / 256, 256, 0, stream>>>(W2, W2t, HID, LAT);

    const int gy = (N_NODES + 63) / 64;   // 782
    const int pgrid = N_NODES / 8;        // 6250 (8 nodes/block)

    // z0h = bf16(x @ Wproj)
    gemm_lds<IN_DIM, 0, true><<<dim3(1, gy), 256, 0, stream>>>(x, Wpt, (unsigned short*)z0h,
                                                               N_NODES, LAT,
                                                               nullptr, nullptr, nullptr, nullptr, nullptr);
    // p0h = bf16(prop(z0))        [ prop(z0 @ W1) == prop(z0) @ W1 ]
    prop_row<0><<<pgrid, 256, 0, stream>>>(z0h, rowoff, csr, nullptr, nullptr, nullptr, p0h,
                                           nullptr, nullptr, nullptr, nullptr, nullptr);
    // h1h = bf16(relu(bn(p0 @ W1 + b1)))
    gemm_lds<LAT, 1, false><<<dim3(2, gy), 256, 0, stream>>>(p0h, W1t, h1h, N_NODES, HID,
                                                             b1, g1, be1, m1, v1);
    // t2h = bf16(h1 @ W2)
    gemm_lds<HID, 0, false><<<dim3(1, gy), 256, 0, stream>>>(h1h, W2t, (unsigned short*)t2h,
                                                             N_NODES, LAT,
                                                             nullptr, nullptr, nullptr, nullptr, nullptr);
    // h2h = bf16(relu(bn(prop(t2) + b2)))
    prop_row<1><<<pgrid, 256, 0, stream>>>(t2h, rowoff, csr, nullptr, nullptr, nullptr, h2h,
                                           b2, g2, be2, m2, v2);

    // APPNP
    const unsigned* cur = h2h;
    for (int it = 0; it < K_ITERS; ++it) {
        if (it == K_ITERS - 1) {
            prop_row<3><<<pgrid, 256, 0, stream>>>(cur, rowoff, csr, h2h, z0h, out_z, z0h,
                                                   nullptr, nullptr, nullptr, nullptr, nullptr);
        } else {
            unsigned* nxt = (it & 1) ? pingB : pingA;
            prop_row<2><<<pgrid, 256, 0, stream>>>(cur, rowoff, csr, h2h, nullptr, nullptr, nxt,
                                                   nullptr, nullptr, nullptr, nullptr, nullptr);
            cur = nxt;
        }
    }

    // adj = sigmoid(z[row] . z[col]) on bf16 mirror (now in z0h), 16 edges/wave
    edge_dot_mfma<<<N_EDGES / 64, 256, 0, stream>>>(z0h, srcE, dstE, out_adj);
}

// Round 17
// 634.471 us; speedup vs baseline: 2.0677x; 2.0677x over previous
//
#include <hip/hip_runtime.h>

#define N_NODES 50000
#define N_EDGES 800000
#define IN_DIM  512
#define HID     256
#define LAT     128
#define K_ITERS 10
#define BN_EPS  1e-5f

typedef __attribute__((ext_vector_type(8))) short bf16x8;
typedef __attribute__((ext_vector_type(4))) float f32x4;

// ---------------- bf16 helpers ----------------
__device__ inline float bflo(unsigned v) { return __builtin_bit_cast(float, v << 16); }
__device__ inline float bfhi(unsigned v) { return __builtin_bit_cast(float, v & 0xffff0000u); }
__device__ inline unsigned f2bf_bits(float f)
{
    unsigned u = __builtin_bit_cast(unsigned, f);
    return (u + 0x7fffu + ((u >> 16) & 1u)) >> 16;   // RTNE
}
__device__ inline unsigned packbf(float x, float y)
{
    return f2bf_bits(x) | (f2bf_bits(y) << 16);
}

// async global->LDS, 16B per lane; LDS dest = uniform base + lane*16
__device__ inline void gload_lds16(const unsigned short* g, unsigned short* l)
{
    __builtin_amdgcn_global_load_lds(
        (const __attribute__((address_space(1))) unsigned int*)g,
        (__attribute__((address_space(3))) unsigned int*)l, 16, 0, 0);
}

// ---------------- edge dtype detect / normalize ----------------
__global__ void detect_dtype_kernel(const int* __restrict__ ei32, int* __restrict__ flag)
{
    __shared__ int any;
    if (threadIdx.x == 0) any = 0;
    __syncthreads();
    int local = 0;
    for (int i = threadIdx.x; i < 4096; i += blockDim.x)
        local |= ei32[2 * i + 1];
    if (local) atomicOr(&any, 1);
    __syncthreads();
    if (threadIdx.x == 0) flag[0] = (any != 0) ? 1 : 0;   // 1 => data is int32
}

__global__ void init_cnt_kernel(int* __restrict__ cnt, int n)
{
    int i = blockIdx.x * blockDim.x + threadIdx.x;
    if (i < n) cnt[i] = 1;   // self-loop
}

// fused convert + degree count
__global__ void convert_count_kernel(const void* __restrict__ ei, const int* __restrict__ flag,
                                     int* __restrict__ srcE, int* __restrict__ dstE,
                                     int* __restrict__ cnt, int E)
{
    int e = blockIdx.x * blockDim.x + threadIdx.x;
    if (e >= E) return;
    int s, d;
    if (*flag) {
        const int* p = (const int*)ei;
        s = p[e]; d = p[E + e];
    } else {
        const long long* p = (const long long*)ei;
        s = (int)p[e]; d = (int)p[E + e];
    }
    srcE[e] = s;
    dstE[e] = d;
    atomicAdd(&cnt[d], 1);
}

// ---------------- parallel scan (3 small kernels) ----------------
__global__ __launch_bounds__(256) void block_sum_kernel(const int* __restrict__ cnt,
                                                        int* __restrict__ bsum, int n)
{
    __shared__ int s[256];
    int i = blockIdx.x * 256 + threadIdx.x;
    s[threadIdx.x] = (i < n) ? cnt[i] : 0;
    __syncthreads();
    for (int off = 128; off > 0; off >>= 1) {
        if (threadIdx.x < off) s[threadIdx.x] += s[threadIdx.x + off];
        __syncthreads();
    }
    if (threadIdx.x == 0) bsum[blockIdx.x] = s[0];
}

__global__ __launch_bounds__(256) void block_scan_kernel(int* __restrict__ bsum, int nb)
{
    __shared__ int s[256];
    int t = threadIdx.x;
    int v = (t < nb) ? bsum[t] : 0;
    s[t] = v;
    __syncthreads();
    for (int off = 1; off < 256; off <<= 1) {
        int u = (t >= off) ? s[t - off] : 0;
        __syncthreads();
        s[t] += u;
        __syncthreads();
    }
    if (t < nb) bsum[t] = s[t] - v;   // exclusive block offsets
}

__global__ __launch_bounds__(256) void final_scan_kernel(const int* __restrict__ cnt,
                                                         const int* __restrict__ bsum,
                                                         int* __restrict__ rowoff,
                                                         int* __restrict__ cursor,
                                                         float* __restrict__ dinv, int n)
{
    __shared__ int s[256];
    int t = threadIdx.x;
    int i = blockIdx.x * 256 + t;
    int c = (i < n) ? cnt[i] : 0;
    s[t] = c;
    __syncthreads();
    for (int off = 1; off < 256; off <<= 1) {
        int u = (t >= off) ? s[t - off] : 0;
        __syncthreads();
        s[t] += u;
        __syncthreads();
    }
    if (i < n) {
        int excl = bsum[blockIdx.x] + s[t] - c;
        rowoff[i] = excl;
        cursor[i] = excl;
        dinv[i] = rsqrtf((float)c);
    }
    if (i == 0) rowoff[n] = N_EDGES + N_NODES;   // total is a constant
}

// csr entry packed: src (16 bits, N<65536) | bf16(w) << 16
__global__ void scatter_kernel(const int* __restrict__ srcE, const int* __restrict__ dstE,
                               const float* __restrict__ dinv, int* __restrict__ cursor,
                               unsigned* __restrict__ csr, int E, int n)
{
    int e = blockIdx.x * blockDim.x + threadIdx.x;
    if (e >= E + n) return;
    int s, d;
    if (e < E) { s = srcE[e]; d = dstE[e]; }
    else       { s = e - E;   d = s; }
    int pos = atomicAdd(&cursor[d], 1);
    float w = dinv[s] * dinv[d];
    csr[pos] = (unsigned)s | (f2bf_bits(w) << 16);
}

// ---- transpose-convert to tile-major bf16: W[K][C] -> [colblk][k/8][128][8] --
__global__ void transpose_cvt_tile(const float* __restrict__ in, unsigned short* __restrict__ out,
                                   int K, int C)
{
    int idx = blockIdx.x * 256 + threadIdx.x;
    if (idx >= K * C) return;
    int k = idx / C, col = idx - k * C;
    int dst = (col >> 7) * (K * 128) + (k >> 3) * 1024 + ((col & 127) << 3) + (k & 7);
    out[dst] = (unsigned short)f2bf_bits(in[idx]);
}

// ---------------- MFMA bf16 GEMM, global_load_lds B-staging ------------------
// 16 rows/wave x 128 cols, 4 waves/block (64-row tile). Grid (Nc/128, ceil(M/64)).
// B pre-laid tile-major so each 64-k chunk (16 KB) is a LINEAR lane-order copy
// -> global_load_lds (no staging registers: nothing to spill or sink).
// Double-buffered LDS, one barrier per chunk. A: 2-deep register prefetch.
template<int KDIM, int EPI, bool AF32>
__global__ __launch_bounds__(256) void gemm_lds(const void* __restrict__ Ain,
                                                const unsigned short* __restrict__ Bt,
                                                unsigned short* __restrict__ Cout,
                                                int M, int Nc,
                                                const float* __restrict__ cb,
                                                const float* __restrict__ cg,
                                                const float* __restrict__ cbe,
                                                const float* __restrict__ cm,
                                                const float* __restrict__ cv)
{
    constexpr int BK = 64;
    constexpr int NC = KDIM / BK;
    __shared__ unsigned short Bl[2][BK * 128];   // 2 x 16 KB
    const int tid  = threadIdx.x;
    const int wave = tid >> 6;
    const int lane = tid & 63;
    const int s  = lane & 15;
    const int kc = lane >> 4;
    const int wrow0   = blockIdx.y * 64 + wave * 16;
    const int colbase = blockIdx.x * 128;
    int arow = wrow0 + s; if (arow > M - 1) arow = M - 1;   // clamp

    const float*          Af   = (const float*)Ain + (size_t)arow * KDIM + 8 * kc;
    const unsigned short* Ahp  = (const unsigned short*)Ain + (size_t)arow * KDIM + 8 * kc;
    const unsigned short* Bblk = Bt + (size_t)blockIdx.x * KDIM * 128;

    float4 Arf[2][2][2];
    bf16x8 Arh[2][2];
    f32x4  acc[8] = {};

    auto stage = [&](int c, int buf) {
#pragma unroll
        for (int i = 0; i < 4; ++i) {
            const int j = wave * 4 + i;
            gload_lds16(Bblk + (size_t)c * 8192 + j * 512 + lane * 8, &Bl[buf][j * 512]);
        }
    };

    stage(0, 0);
#pragma unroll
    for (int kk = 0; kk < 2; ++kk) {
        if constexpr (AF32) {
            Arf[0][kk][0] = *(const float4*)(Af + 32 * kk);
            Arf[0][kk][1] = *(const float4*)(Af + 32 * kk + 4);
        } else {
            Arh[0][kk] = *(const bf16x8*)(Ahp + 32 * kk);
        }
    }
    __syncthreads();   // drains chunk-0 DMA

#pragma unroll
    for (int c = 0; c < NC; ++c) {
        if (c + 1 < NC) {
            stage(c + 1, (c + 1) & 1);
#pragma unroll
            for (int kk = 0; kk < 2; ++kk) {
                if constexpr (AF32) {
                    Arf[(c + 1) & 1][kk][0] = *(const float4*)(Af + (c + 1) * 64 + 32 * kk);
                    Arf[(c + 1) & 1][kk][1] = *(const float4*)(Af + (c + 1) * 64 + 32 * kk + 4);
                } else {
                    Arh[(c + 1) & 1][kk] = *(const bf16x8*)(Ahp + (c + 1) * 64 + 32 * kk);
                }
            }
        }
#pragma unroll
        for (int kk = 0; kk < 2; ++kk) {
            bf16x8 af;
            if constexpr (AF32) {
                float4 u0 = Arf[c & 1][kk][0];
                float4 u1 = Arf[c & 1][kk][1];
                af[0] = (short)f2bf_bits(u0.x); af[1] = (short)f2bf_bits(u0.y);
                af[2] = (short)f2bf_bits(u0.z); af[3] = (short)f2bf_bits(u0.w);
                af[4] = (short)f2bf_bits(u1.x); af[5] = (short)f2bf_bits(u1.y);
                af[6] = (short)f2bf_bits(u1.z); af[7] = (short)f2bf_bits(u1.w);
            } else {
                af = Arh[c & 1][kk];
            }
#pragma unroll
            for (int t = 0; t < 8; ++t) {
                bf16x8 bf = *(const bf16x8*)&Bl[c & 1][((kk * 4 + kc) * 128 + t * 16 + s) * 8];
                acc[t] = __builtin_amdgcn_mfma_f32_16x16x32_bf16(af, bf, acc[t], 0, 0, 0);
            }
        }
        __syncthreads();
    }

#pragma unroll
    for (int t = 0; t < 8; ++t) {
        const int col = colbase + t * 16 + s;
        float sc = 1.f, sh = 0.f;
        if (EPI == 1) {
            sc = cg[col] * rsqrtf(cv[col] + BN_EPS);
            sh = (cb[col] - cm[col]) * sc + cbe[col];
        }
#pragma unroll
        for (int j = 0; j < 4; ++j) {
            const int crow = wrow0 + kc * 4 + j;
            if (crow < M) {
                float xv = acc[t][j];
                if (EPI == 1) xv = fmaxf(fmaf(xv, sc, sh), 0.f);
                Cout[(size_t)crow * Nc + col] = (unsigned short)f2bf_bits(xv);
            }
        }
    }
}

// ---------------- full-row propagate, 2 nodes/wave, deep-ILP -----------------
// Half-wave (32 lanes) per node: 2 edge-groups x 16 lanes; lane covers dims
// 8s..8s+7 (uint4). Gather batch depth 8 (avg deg/group = 8.5 -> batch ~full).
// csr 4B packed (src:16 | bf16(w):16).
// MODE 0: out bf16. MODE 1: bn+relu -> bf16. MODE 2: 0.9a+0.1h2 -> bf16.
// MODE 3: final: f32 z to outf, bf16 mirror to outh (aliases z0h).
template<int MODE>
__global__ __launch_bounds__(256) void prop_row(const unsigned* __restrict__ in,
                                                const int* __restrict__ rowoff,
                                                const unsigned* __restrict__ csr,
                                                const unsigned* __restrict__ h2h,
                                                const unsigned* __restrict__ z0h,
                                                float* __restrict__ outf,
                                                unsigned* __restrict__ outh,
                                                const float* __restrict__ bb,
                                                const float* __restrict__ bg,
                                                const float* __restrict__ bbe,
                                                const float* __restrict__ bm,
                                                const float* __restrict__ bv)
{
    const int node = blockIdx.x * 8 + (threadIdx.x >> 5);   // half-wave -> node
    const int lane = threadIdx.x & 31;
    const int g = lane >> 4, s = lane & 15;
    const int e0 = rowoff[node], e1 = rowoff[node + 1];

    float f[8] = {};
    int e = e0 + g;
    while (e < e1) {
        unsigned P[8];
        uint4 V[8];
#pragma unroll
        for (int i = 0; i < 8; ++i) { P[i] = 0; V[i] = make_uint4(0u, 0u, 0u, 0u); }
#pragma unroll
        for (int i = 0; i < 8; ++i)
            if (e + 2 * i < e1) P[i] = csr[e + 2 * i];
#pragma unroll
        for (int i = 0; i < 8; ++i)
            if (e + 2 * i < e1) V[i] = *(const uint4*)&in[(size_t)(P[i] & 0xFFFFu) * 64 + 4 * s];
#pragma unroll
        for (int i = 0; i < 8; ++i) {
            const float w = __builtin_bit_cast(float, P[i] & 0xffff0000u);
            f[0] = fmaf(w, bflo(V[i].x), f[0]); f[1] = fmaf(w, bfhi(V[i].x), f[1]);
            f[2] = fmaf(w, bflo(V[i].y), f[2]); f[3] = fmaf(w, bfhi(V[i].y), f[3]);
            f[4] = fmaf(w, bflo(V[i].z), f[4]); f[5] = fmaf(w, bfhi(V[i].z), f[5]);
            f[6] = fmaf(w, bflo(V[i].w), f[6]); f[7] = fmaf(w, bfhi(V[i].w), f[7]);
        }
        e += 16;
    }
#pragma unroll
    for (int i = 0; i < 8; ++i)
        f[i] += __shfl_xor(f[i], 16, 64);   // combine the node's 2 groups

    if (g == 0) {
        const size_t o = (size_t)node * 64 + 4 * s;
        uint4 ov;
        if (MODE == 0) {
            ov.x = packbf(f[0], f[1]); ov.y = packbf(f[2], f[3]);
            ov.z = packbf(f[4], f[5]); ov.w = packbf(f[6], f[7]);
            *(uint4*)&outh[o] = ov;
        } else if (MODE == 1) {
            float4 G0 = *(const float4*)&bg[8 * s],  G1 = *(const float4*)&bg[8 * s + 4];
            float4 V0 = *(const float4*)&bv[8 * s],  V1 = *(const float4*)&bv[8 * s + 4];
            float4 B0 = *(const float4*)&bb[8 * s],  B1 = *(const float4*)&bb[8 * s + 4];
            float4 M0 = *(const float4*)&bm[8 * s],  M1 = *(const float4*)&bm[8 * s + 4];
            float4 E0 = *(const float4*)&bbe[8 * s], E1 = *(const float4*)&bbe[8 * s + 4];
            float gg[8] = {G0.x, G0.y, G0.z, G0.w, G1.x, G1.y, G1.z, G1.w};
            float vv[8] = {V0.x, V0.y, V0.z, V0.w, V1.x, V1.y, V1.z, V1.w};
            float bbv[8] = {B0.x, B0.y, B0.z, B0.w, B1.x, B1.y, B1.z, B1.w};
            float mm[8] = {M0.x, M0.y, M0.z, M0.w, M1.x, M1.y, M1.z, M1.w};
            float ee[8] = {E0.x, E0.y, E0.z, E0.w, E1.x, E1.y, E1.z, E1.w};
            float r[8];
#pragma unroll
            for (int i = 0; i < 8; ++i) {
                float sc = gg[i] * rsqrtf(vv[i] + BN_EPS);
                float sh = (bbv[i] - mm[i]) * sc + ee[i];
                r[i] = fmaxf(fmaf(f[i], sc, sh), 0.f);
            }
            ov.x = packbf(r[0], r[1]); ov.y = packbf(r[2], r[3]);
            ov.z = packbf(r[4], r[5]); ov.w = packbf(r[6], r[7]);
            *(uint4*)&outh[o] = ov;
        } else if (MODE == 2) {
            uint4 hv = *(const uint4*)&h2h[o];
            ov.x = packbf(fmaf(0.9f, f[0], 0.1f * bflo(hv.x)), fmaf(0.9f, f[1], 0.1f * bfhi(hv.x)));
            ov.y = packbf(fmaf(0.9f, f[2], 0.1f * bflo(hv.y)), fmaf(0.9f, f[3], 0.1f * bfhi(hv.y)));
            ov.z = packbf(fmaf(0.9f, f[4], 0.1f * bflo(hv.z)), fmaf(0.9f, f[5], 0.1f * bfhi(hv.z)));
            ov.w = packbf(fmaf(0.9f, f[6], 0.1f * bflo(hv.w)), fmaf(0.9f, f[7], 0.1f * bfhi(hv.w)));
            *(uint4*)&outh[o] = ov;
        } else {
            uint4 hv = *(const uint4*)&h2h[o];
            uint4 zv = *(const uint4*)&z0h[o];
            float r[8];
            r[0] = fmaf(0.9f, f[0], 0.1f * bflo(hv.x)) + bflo(zv.x);
            r[1] = fmaf(0.9f, f[1], 0.1f * bfhi(hv.x)) + bfhi(zv.x);
            r[2] = fmaf(0.9f, f[2], 0.1f * bflo(hv.y)) + bflo(zv.y);
            r[3] = fmaf(0.9f, f[3], 0.1f * bfhi(hv.y)) + bfhi(zv.y);
            r[4] = fmaf(0.9f, f[4], 0.1f * bflo(hv.z)) + bflo(zv.z);
            r[5] = fmaf(0.9f, f[5], 0.1f * bfhi(hv.z)) + bfhi(zv.z);
            r[6] = fmaf(0.9f, f[6], 0.1f * bflo(hv.w)) + bflo(zv.w);
            r[7] = fmaf(0.9f, f[7], 0.1f * bfhi(hv.w)) + bfhi(zv.w);
            *(float4*)&outf[(size_t)node * LAT + 8 * s]     = make_float4(r[0], r[1], r[2], r[3]);
            *(float4*)&outf[(size_t)node * LAT + 8 * s + 4] = make_float4(r[4], r[5], r[6], r[7]);
            ov.x = packbf(r[0], r[1]); ov.y = packbf(r[2], r[3]);
            ov.z = packbf(r[4], r[5]); ov.w = packbf(r[6], r[7]);
            *(uint4*)&outh[o] = ov;
        }
    }
}

// ---------------- MFMA edge dot: 16 edges per wave, row-major z --------------
__global__ __launch_bounds__(256) void edge_dot_mfma(const unsigned* __restrict__ zh,
                                                     const int* __restrict__ srcE,
                                                     const int* __restrict__ dstE,
                                                     float* __restrict__ adj)
{
    const int gw = blockIdx.x * 4 + (threadIdx.x >> 6);
    const int base = gw * 16;
    const int lane = threadIdx.x & 63;
    const int s = lane & 15, kc = lane >> 4;
    const int r = srcE[base + s];
    const int c = dstE[base + s];
    const unsigned* zr = &zh[(size_t)r * 64 + 4 * kc];
    const unsigned* zc = &zh[(size_t)c * 64 + 4 * kc];
    f32x4 acc = {};
#pragma unroll
    for (int k0 = 0; k0 < 4; ++k0) {
        bf16x8 af = *(const bf16x8*)(zr + 16 * k0);
        bf16x8 bf = *(const bf16x8*)(zc + 16 * k0);
        acc = __builtin_amdgcn_mfma_f32_16x16x32_bf16(af, bf, acc, 0, 0, 0);
    }
    if ((s >> 2) == kc) {
        const int j = s & 3;
        float v = (j == 0) ? acc[0] : (j == 1) ? acc[1] : (j == 2) ? acc[2] : acc[3];
        adj[base + s] = 1.f / (1.f + expf(-v));
    }
}

// ---------------- launcher ----------------
extern "C" void kernel_launch(void* const* d_in, const int* in_sizes, int n_in,
                              void* d_out, int out_size, void* d_ws, size_t ws_size,
                              hipStream_t stream)
{
    const float* x     = (const float*)d_in[0];
    const void*  ei    = d_in[1];
    const float* Wproj = (const float*)d_in[2];
    const float* W1    = (const float*)d_in[3];
    const float* b1    = (const float*)d_in[4];
    const float* g1    = (const float*)d_in[5];
    const float* be1   = (const float*)d_in[6];
    const float* m1    = (const float*)d_in[7];
    const float* v1    = (const float*)d_in[8];
    const float* W2    = (const float*)d_in[9];
    const float* b2    = (const float*)d_in[10];
    const float* g2    = (const float*)d_in[11];
    const float* be2   = (const float*)d_in[12];
    const float* m2    = (const float*)d_in[13];
    const float* v2    = (const float*)d_in[14];

    float* out_adj = (float*)d_out;
    float* out_z   = (float*)d_out + N_EDGES;

    char* w = (char*)d_ws;
    size_t off = 0;
    auto alloc = [&](size_t bytes) {
        void* p = w + off;
        off += (bytes + 255) & ~(size_t)255;
        return p;
    };
    const size_t NB = (size_t)N_NODES * 64 * 4;   // one bf16 [N,128] plane = 12.8 MB
    const int NBLK = (N_NODES + 255) / 256;       // 196

    int*            flag   = (int*)           alloc(4);
    int*            cnt    = (int*)           alloc((size_t)N_NODES * 4);
    int*            cursor = (int*)           alloc((size_t)N_NODES * 4);
    int*            rowoff = (int*)           alloc((size_t)(N_NODES + 1) * 4);
    float*          dinv   = (float*)         alloc((size_t)N_NODES * 4);
    int*            bsum   = (int*)           alloc(256 * 4);
    int*            srcE   = (int*)           alloc((size_t)N_EDGES * 4);
    int*            dstE   = (int*)           alloc((size_t)N_EDGES * 4);
    unsigned*       csr    = (unsigned*)      alloc((size_t)(N_EDGES + N_NODES) * 4);
    unsigned short* Wpt    = (unsigned short*)alloc((size_t)LAT * IN_DIM * 2);
    unsigned short* W1t    = (unsigned short*)alloc((size_t)HID * LAT * 2);
    unsigned short* W2t    = (unsigned short*)alloc((size_t)LAT * HID * 2);
    unsigned*       z0h    = (unsigned*)      alloc(NB);       // z0 bf16; final z mirror
    unsigned*       p0h    = (unsigned*)      alloc(NB);
    unsigned short* h1h    = (unsigned short*)alloc(2 * NB);   // [N,256]; later pingA/pingB
    unsigned*       t2h    = (unsigned*)      alloc(NB);
    unsigned*       h2h    = (unsigned*)      alloc(NB);

    unsigned* pingA = (unsigned*)h1h;
    unsigned* pingB = (unsigned*)h1h + N_NODES * 64;

    // graph preprocessing
    detect_dtype_kernel<<<1, 256, 0, stream>>>((const int*)ei, flag);
    init_cnt_kernel<<<(N_NODES + 255) / 256, 256, 0, stream>>>(cnt, N_NODES);
    convert_count_kernel<<<(N_EDGES + 255) / 256, 256, 0, stream>>>(ei, flag, srcE, dstE, cnt, N_EDGES);
    block_sum_kernel<<<NBLK, 256, 0, stream>>>(cnt, bsum, N_NODES);
    block_scan_kernel<<<1, 256, 0, stream>>>(bsum, NBLK);
    final_scan_kernel<<<NBLK, 256, 0, stream>>>(cnt, bsum, rowoff, cursor, dinv, N_NODES);
    scatter_kernel<<<(N_EDGES + N_NODES + 255) / 256, 256, 0, stream>>>(srcE, dstE, dinv, cursor,
                                                                        csr, N_EDGES, N_NODES);

    // weight transposes (f32 -> bf16, tile-major [colblk][k/8][128][8])
    transpose_cvt_tile<<<(IN_DIM * LAT + 255) / 256, 256, 0, stream>>>(Wproj, Wpt, IN_DIM, LAT);
    transpose_cvt_tile<<<(LAT * HID + 255) / 256, 256, 0, stream>>>(W1, W1t, LAT, HID);
    transpose_cvt_tile<<<(HID * LAT + 255) / 256, 256, 0, stream>>>(W2, W2t, HID, LAT);

    const int gy = (N_NODES + 63) / 64;   // 782
    const int pgrid = N_NODES / 8;        // 6250 (8 nodes/block)

    // z0h = bf16(x @ Wproj)
    gemm_lds<IN_DIM, 0, true><<<dim3(1, gy), 256, 0, stream>>>(x, Wpt, (unsigned short*)z0h,
                                                               N_NODES, LAT,
                                                               nullptr, nullptr, nullptr, nullptr, nullptr);
    // p0h = bf16(prop(z0))        [ prop(z0 @ W1) == prop(z0) @ W1 ]
    prop_row<0><<<pgrid, 256, 0, stream>>>(z0h, rowoff, csr, nullptr, nullptr, nullptr, p0h,
                                           nullptr, nullptr, nullptr, nullptr, nullptr);
    // h1h = bf16(relu(bn(p0 @ W1 + b1)))
    gemm_lds<LAT, 1, false><<<dim3(2, gy), 256, 0, stream>>>(p0h, W1t, h1h, N_NODES, HID,
                                                             b1, g1, be1, m1, v1);
    // t2h = bf16(h1 @ W2)
    gemm_lds<HID, 0, false><<<dim3(1, gy), 256, 0, stream>>>(h1h, W2t, (unsigned short*)t2h,
                                                             N_NODES, LAT,
                                                             nullptr, nullptr, nullptr, nullptr, nullptr);
    // h2h = bf16(relu(bn(prop(t2) + b2)))
    prop_row<1><<<pgrid, 256, 0, stream>>>(t2h, rowoff, csr, nullptr, nullptr, nullptr, h2h,
                                           b2, g2, be2, m2, v2);

    // APPNP
    const unsigned* cur = h2h;
    for (int it = 0; it < K_ITERS; ++it) {
        if (it == K_ITERS - 1) {
            prop_row<3><<<pgrid, 256, 0, stream>>>(cur, rowoff, csr, h2h, z0h, out_z, z0h,
                                                   nullptr, nullptr, nullptr, nullptr, nullptr);
        } else {
            unsigned* nxt = (it & 1) ? pingB : pingA;
            prop_row<2><<<pgrid, 256, 0, stream>>>(cur, rowoff, csr, h2h, nullptr, nullptr, nxt,
                                                   nullptr, nullptr, nullptr, nullptr, nullptr);
            cur = nxt;
        }
    }

    // adj = sigmoid(z[row] . z[col]) on bf16 mirror (now in z0h), 16 edges/wave
    edge_dot_mfma<<<N_EDGES / 64, 256, 0, stream>>>(z0h, srcE, dstE, out_adj);
}